// Round 11
// baseline (86.670 us; speedup 1.0000x reference)
//
#include <hip/hip_runtime.h>
#include <cfloat>
#include <math.h>

#define SB 1024   // sequence length S = H*W
#define CC 512    // channels
#define NB 8      // batch
#define NH 8      // heads
#define HD 64     // head dim

typedef short short8 __attribute__((ext_vector_type(8)));
typedef short s16x4 __attribute__((ext_vector_type(4)));
typedef float f32x4 __attribute__((ext_vector_type(4)));

__device__ __forceinline__ short f2bs(float f) {
    union { float f; unsigned u; } x; x.f = f;
    unsigned r = x.u + 0x7fffu + ((x.u >> 16) & 1u);   // RNE to bf16
    return (short)(r >> 16);
}

__device__ __forceinline__ void gload16(const void* g, void* l) {
    __builtin_amdgcn_global_load_lds(
        (const __attribute__((address_space(1))) unsigned int*)g,
        (__attribute__((address_space(3))) unsigned int*)l, 16, 0, 0);
}

// swizzled short-index within a [rows][64-short] LDS tile (128B rows)
__device__ __forceinline__ int sidx(int row, int colb) {
    return row * 64 + ((colb ^ ((row & 7) << 4)) >> 1);
}

// ---------------------------------------------------------------------------
// prep: fused auxiliary pass.
//   blocks [0,1024):    weights fp32 -> bf16
//   blocks [1024,2048): x (B,C,S) fp32 -> xT (B,S,C) bf16 (tile transpose)
//   blocks [2048,2080): mask -> float 0/-FLT_MAX
//   blocks [2080,2096): zero vmean accumulator (gemm0 atomically adds)
// ---------------------------------------------------------------------------
__global__ __launch_bounds__(256)
void prep(const float* __restrict__ w1, const float* __restrict__ w2,
          short* __restrict__ o1, short* __restrict__ o2,
          const float* __restrict__ x, short* __restrict__ xT,
          const int* __restrict__ mask, float* __restrict__ maskf,
          float* __restrict__ vmean)
{
    const int B = blockIdx.x;
    const int tid = threadIdx.x;
    if (B < 1024) {
        const int i4 = B * 256 + tid;
        const int N1 = 1536 * 512 / 4;
        if (i4 < N1) {
            float4 v = *(const float4*)&w1[(size_t)i4 * 4];
            s16x4 p; p[0] = f2bs(v.x); p[1] = f2bs(v.y); p[2] = f2bs(v.z); p[3] = f2bs(v.w);
            *(s16x4*)&o1[(size_t)i4 * 4] = p;
        } else {
            const int j = i4 - N1;
            float4 v = *(const float4*)&w2[(size_t)j * 4];
            s16x4 p; p[0] = f2bs(v.x); p[1] = f2bs(v.y); p[2] = f2bs(v.z); p[3] = f2bs(v.w);
            *(s16x4*)&o2[(size_t)j * 4] = p;
        }
    } else if (B < 2048) {
        const int idx = B - 1024;
        const int bs = idx & 15, bc = (idx >> 4) & 7, b = idx >> 7;
        __shared__ short T[64][72];
        {
            const int cl = tid >> 4;
            const int s4 = (tid & 15) * 4;
            #pragma unroll
            for (int r = 0; r < 4; ++r) {
                const int c = cl + 16 * r;
                float4 v = *(const float4*)&x[((size_t)b * CC + bc * 64 + c) * SB + bs * 64 + s4];
                T[s4 + 0][c] = f2bs(v.x); T[s4 + 1][c] = f2bs(v.y);
                T[s4 + 2][c] = f2bs(v.z); T[s4 + 3][c] = f2bs(v.w);
            }
        }
        __syncthreads();
        {
            const int sl = tid >> 2;
            const int c16 = (tid & 3) * 16;
            short8 v0 = *(const short8*)&T[sl][c16];
            short8 v1 = *(const short8*)&T[sl][c16 + 8];
            short* dst = &xT[((size_t)b * SB + bs * 64 + sl) * CC + bc * 64 + c16];
            *(short8*)&dst[0] = v0;
            *(short8*)&dst[8] = v1;
        }
    } else if (B < 2080) {
        const int gi = (B - 2048) * 256 + tid;
        if (gi < NB * SB) maskf[gi] = (mask[gi] != 0) ? -FLT_MAX : 0.f;
    } else {
        const int i = (B - 2080) * 256 + tid;
        if (i < NB * CC) vmean[i] = 0.f;
    }
}

// ---------------------------------------------------------------------------
// bf16 MFMA GEMM: Y[b,o,s] = sum_c A[o,c] * X[b,s,c]^T + bias[o]
// 128x128 tile, BK=64, 4 waves (2x2), 4x4 16x16 frags per wave.
// MODE 0 (qkv): o<512 -> qT[b,h,s,d] * (0.125*log2e); o<1024 -> kT[b,h,s,d];
//               else v[b,c,s] + fp32 atomic partial sums into vmean[b][c]
//               (RAW column sums; attn scales by 1/1024 at use).
// MODE 1 (proj): fp32 out[b,o,s].
// ---------------------------------------------------------------------------
template<int MODE>
__global__ __launch_bounds__(256)
void gemm_bf16(const short* __restrict__ A, const float* __restrict__ bias,
               const short* __restrict__ BT,
               short* __restrict__ qTo, short* __restrict__ kTo,
               short* __restrict__ vo, float* __restrict__ fo,
               float* __restrict__ vmean)
{
    const int stile = blockIdx.x * 128;
    const int bo    = blockIdx.y;
    const int b     = blockIdx.z;
    const int tid   = threadIdx.x;
    const int wave = tid >> 6, lane = tid & 63, lg = lane >> 4, ln = lane & 15;
    const int wm = wave >> 1, wn = wave & 1;

    __shared__ short Al[128 * 64];
    __shared__ short Bl[128 * 64];

    f32x4 acc[4][4];
    #pragma unroll
    for (int mt = 0; mt < 4; ++mt)
        #pragma unroll
        for (int nt = 0; nt < 4; ++nt) acc[mt][nt] = (f32x4){0.f, 0.f, 0.f, 0.f};

    const char* Ab = (const char*)(A + (size_t)bo * 128 * 512);
    const char* Bb = (const char*)(BT + ((size_t)b * SB + stile) * 512);

    for (int kc = 0; kc < 512; kc += 64) {
        __syncthreads();
        #pragma unroll
        for (int sw = 0; sw < 4; ++sw) {
            const int lin = tid * 16 + sw * 4096;
            const int row = lin >> 7;
            const int scol = (lin & 127) ^ ((row & 7) << 4);
            gload16(Ab + ((size_t)row * 512 + kc) * 2 + scol,
                    (char*)Al + (wave << 10) + (sw << 12));
            gload16(Bb + ((size_t)row * 512 + kc) * 2 + scol,
                    (char*)Bl + (wave << 10) + (sw << 12));
        }
        __syncthreads();
        #pragma unroll
        for (int kk = 0; kk < 2; ++kk) {
            const int colb = kk * 64 + lg * 16;
            short8 a[4], bb[4];
            #pragma unroll
            for (int mt = 0; mt < 4; ++mt)
                a[mt] = *(const short8*)&Al[sidx(wm * 64 + mt * 16 + ln, colb)];
            #pragma unroll
            for (int nt = 0; nt < 4; ++nt)
                bb[nt] = *(const short8*)&Bl[sidx(wn * 64 + nt * 16 + ln, colb)];
            #pragma unroll
            for (int mt = 0; mt < 4; ++mt)
                #pragma unroll
                for (int nt = 0; nt < 4; ++nt)
                    acc[mt][nt] = __builtin_amdgcn_mfma_f32_16x16x32_bf16(
                        a[mt], bb[nt], acc[mt][nt], 0, 0, 0);
        }
    }

    const int s_base = stile + wn * 64;
    if (MODE == 0) {
        if (bo < 8) {   // q or k -> transposed [b,h,s,d]
            short* dst = (bo < 4) ? qTo : kTo;
            const int h = (bo & 3) * 2 + wm;
            const float sc = (bo < 4) ? 0.18033688011112042f : 1.0f;  // 0.125*log2(e)
            #pragma unroll
            for (int mt = 0; mt < 4; ++mt) {
                const int d0 = mt * 16 + 4 * lg;
                const int o0 = bo * 128 + wm * 64 + d0;
                const float b0 = bias[o0], b1 = bias[o0 + 1],
                            b2 = bias[o0 + 2], b3 = bias[o0 + 3];
                #pragma unroll
                for (int nt = 0; nt < 4; ++nt) {
                    const int s = s_base + nt * 16 + ln;
                    s16x4 pk;
                    pk[0] = f2bs((acc[mt][nt][0] + b0) * sc);
                    pk[1] = f2bs((acc[mt][nt][1] + b1) * sc);
                    pk[2] = f2bs((acc[mt][nt][2] + b2) * sc);
                    pk[3] = f2bs((acc[mt][nt][3] + b3) * sc);
                    *(s16x4*)&dst[(((size_t)b * NH + h) * SB + s) * HD + d0] = pk;
                }
            }
        } else {        // v -> natural [b,c,s] + vmean partial sums
            #pragma unroll
            for (int mt = 0; mt < 4; ++mt) {
                const int cv0 = (bo - 8) * 128 + wm * 64 + mt * 16 + 4 * lg;
                #pragma unroll
                for (int r = 0; r < 4; ++r) {
                    const float bv = bias[1024 + cv0 + r];
                    float part = 0.f;
                    #pragma unroll
                    for (int nt = 0; nt < 4; ++nt) {
                        const int s = s_base + nt * 16 + ln;
                        const float val = acc[mt][nt][r] + bv;
                        part += val;
                        vo[((size_t)b * CC + cv0 + r) * SB + s] = f2bs(val);
                    }
                    // reduce over the 16 ln-lanes of this lg group
                    #pragma unroll
                    for (int o = 1; o < 16; o <<= 1)
                        part += __shfl_xor(part, o, 64);
                    if (ln == 0)
                        atomicAdd(&vmean[(size_t)b * CC + cv0 + r], part);
                }
            }
        }
    } else {            // proj -> fp32 out [b,o,s]
        #pragma unroll
        for (int mt = 0; mt < 4; ++mt) {
            #pragma unroll
            for (int r = 0; r < 4; ++r) {
                const int o = bo * 128 + wm * 64 + mt * 16 + 4 * lg + r;
                const float bv = bias[o];
                #pragma unroll
                for (int nt = 0; nt < 4; ++nt) {
                    const int s = s_base + nt * 16 + ln;
                    fo[((size_t)b * CC + o) * SB + s] = acc[mt][nt][r] + bv;
                }
            }
        }
    }
}

// ---------------------------------------------------------------------------
// Paired-q-tile double-buffered MFMA attention, fully owner-lane.
//  - Block = (pa, bh) handles q-tiles A=pa and B=15-pa in the SAME tile loop:
//    every block does exactly 17 tile-computations (perfect balance); K/V
//    LDS fragments and staging are SHARED between sets; set A's softmax
//    (VALU) overlaps set B's MFMA within the wave (2x ILP, same occupancy).
//  - QK^T as mfma(K,Q); PV as mfma(V,P): lane ln owns query ln's scores,
//    softmax state, and ctx accumulator. 2+2 shfl_xor per set per tile.
//  - Defer-max (T13): skip rescale when __all(pmax <= m_+11.5) (exp2 dom).
//  - Fully-masked rows keep m == -FLT_MAX -> ctx = vmean/1024 (reference's
//    uniform softmax over all 1024 keys). vmean holds RAW column sums.
// ---------------------------------------------------------------------------
__global__ __launch_bounds__(256, 3)
void attn_mfma(const short* __restrict__ qT, const short* __restrict__ kT,
               const short* __restrict__ vN, const float* __restrict__ maskf,
               const float* __restrict__ vmean, short* __restrict__ ctxT)
{
    const int L  = blockIdx.x;            // 512 blocks
    const int pa = L >> 6;                // 0..7 (heavy staging first)
    const int bh = L & 63;                // XCD = L%8 = h
    const int qbA = pa, qbB = 15 - pa;
    const int b  = bh >> 3, h = bh & 7;
    const int tid = threadIdx.x;
    const int wave = tid >> 6;
    const int lane = tid & 63;
    const int lg = lane >> 4;
    const int ln = lane & 15;

    __shared__ short Ks[2][64 * 64];      // [buf][t][d] swizzled
    __shared__ short Vs[2][64 * 64];      // [buf][d][t] swizzled
    __shared__ float mskL[2][64];
    __shared__ short Ps[4][2][16][72];    // [wave][set][q][t]

    const char*  kbh = (const char*)(kT + (((size_t)b * NH + h) * SB) * HD);
    const char*  vbh = (const char*)(vN + ((size_t)b * CC + h * HD) * SB);
    const float* mb  = maskf + (size_t)b * SB;

    short8 qaA0, qaA1, qaB0, qaB1;
    {
        const short* qra = qT + (((size_t)b * NH + h) * SB + qbA * 64 + wave * 16 + ln) * HD;
        qaA0 = *(const short8*)&qra[8 * lg];
        qaA1 = *(const short8*)&qra[32 + 8 * lg];
        const short* qrb = qT + (((size_t)b * NH + h) * SB + qbB * 64 + wave * 16 + ln) * HD;
        qaB0 = *(const short8*)&qrb[8 * lg];
        qaB1 = *(const short8*)&qrb[32 + 8 * lg];
    }

    float mA = -FLT_MAX, lA = 0.f, mB = -FLT_MAX, lB = 0.f;
    f32x4 accA[4], accB[4];
    #pragma unroll
    for (int nt = 0; nt < 4; ++nt) {
        accA[nt] = (f32x4){0.f, 0.f, 0.f, 0.f};
        accB[nt] = (f32x4){0.f, 0.f, 0.f, 0.f};
    }

    auto stage = [&](int tb, int bi) {
        #pragma unroll
        for (int sw = 0; sw < 2; ++sw) {
            const int lin = tid * 16 + sw * 4096;
            const int row = lin >> 7;
            const int scol = (lin & 127) ^ ((row & 7) << 4);
            gload16(kbh + (size_t)tb * 128 + row * 128 + scol,
                    (char*)&Ks[bi][0] + (wave << 10) + (sw << 12));
            gload16(vbh + (size_t)row * (SB * 2) + tb * 2 + scol,
                    (char*)&Vs[bi][0] + (wave << 10) + (sw << 12));
        }
        if (tid < 64) mskL[bi][tid] = mb[tb + tid];
    };

    int cur = 0;
    stage(0, 0);
    __syncthreads();

    for (int t = 0; t <= qbB; ++t) {
        if (t < qbB) stage((t + 1) * 64, cur ^ 1);
        const bool doA = (t <= qbA);

        // ---- QK^T for both sets from SHARED K fragments ----
        f32x4 scA[4], scB[4];
        #pragma unroll
        for (int nt = 0; nt < 4; ++nt) {
            short8 kb0 = *(const short8*)&Ks[cur][sidx(ln + 16 * nt, lg * 16)];
            short8 kb1 = *(const short8*)&Ks[cur][sidx(ln + 16 * nt, 64 + lg * 16)];
            f32x4 zb = (f32x4){0.f, 0.f, 0.f, 0.f};
            zb = __builtin_amdgcn_mfma_f32_16x16x32_bf16(kb0, qaB0, zb, 0, 0, 0);
            zb = __builtin_amdgcn_mfma_f32_16x16x32_bf16(kb1, qaB1, zb, 0, 0, 0);
            scB[nt] = zb;
            if (doA) {
                f32x4 za = (f32x4){0.f, 0.f, 0.f, 0.f};
                za = __builtin_amdgcn_mfma_f32_16x16x32_bf16(kb0, qaA0, za, 0, 0, 0);
                za = __builtin_amdgcn_mfma_f32_16x16x32_bf16(kb1, qaA1, za, 0, 0, 0);
                scA[nt] = za;
            }
        }

        // ---- padding mask (shared) + causal diag per set ----
        #pragma unroll
        for (int nt = 0; nt < 4; ++nt) {
            const float4 mf = *(const float4*)&mskL[cur][16 * nt + 4 * lg];
            scB[nt][0] += mf.x; scB[nt][1] += mf.y;
            scB[nt][2] += mf.z; scB[nt][3] += mf.w;
            if (doA) {
                scA[nt][0] += mf.x; scA[nt][1] += mf.y;
                scA[nt][2] += mf.z; scA[nt][3] += mf.w;
            }
        }
        const int so = wave * 16 + ln;
        if (t == qbA) {
            #pragma unroll
            for (int nt = 0; nt < 4; ++nt)
                #pragma unroll
                for (int r = 0; r < 4; ++r)
                    if (16 * nt + 4 * lg + r > so) scA[nt][r] = -FLT_MAX;
        }
        if (t == qbB) {
            #pragma unroll
            for (int nt = 0; nt < 4; ++nt)
                #pragma unroll
                for (int r = 0; r < 4; ++r)
                    if (16 * nt + 4 * lg + r > so) scB[nt][r] = -FLT_MAX;
        }

        // ---- softmax A (VALU) -- independent of softmax B: interleaves ----
        if (doA) {
            float mx = scA[0][0];
            #pragma unroll
            for (int nt = 0; nt < 4; ++nt)
                #pragma unroll
                for (int r = 0; r < 4; ++r)
                    if (nt | r) mx = fmaxf(mx, scA[nt][r]);
            mx = fmaxf(mx, __shfl_xor(mx, 16, 64));
            mx = fmaxf(mx, __shfl_xor(mx, 32, 64));
            if (!__all(mx <= mA + 11.5f)) {
                const float mnew = fmaxf(mA, mx);
                const float fq = exp2f(mA - mnew);
                lA *= fq;
                #pragma unroll
                for (int nt = 0; nt < 4; ++nt)
                    #pragma unroll
                    for (int r = 0; r < 4; ++r) accA[nt][r] *= fq;
                mA = mnew;
            }
            float rs = 0.f;
            #pragma unroll
            for (int nt = 0; nt < 4; ++nt) {
                s16x4 pk;
                #pragma unroll
                for (int r = 0; r < 4; ++r) {
                    const float p = exp2f(scA[nt][r] - mA);
                    rs += p;
                    pk[r] = f2bs(p);
                }
                *(s16x4*)&Ps[wave][0][ln][16 * nt + 4 * lg] = pk;
            }
            rs += __shfl_xor(rs, 16, 64);
            rs += __shfl_xor(rs, 32, 64);
            lA += rs;
        }

        // ---- softmax B ----
        {
            float mx = scB[0][0];
            #pragma unroll
            for (int nt = 0; nt < 4; ++nt)
                #pragma unroll
                for (int r = 0; r < 4; ++r)
                    if (nt | r) mx = fmaxf(mx, scB[nt][r]);
            mx = fmaxf(mx, __shfl_xor(mx, 16, 64));
            mx = fmaxf(mx, __shfl_xor(mx, 32, 64));
            if (!__all(mx <= mB + 11.5f)) {
                const float mnew = fmaxf(mB, mx);
                const float fq = exp2f(mB - mnew);
                lB *= fq;
                #pragma unroll
                for (int nt = 0; nt < 4; ++nt)
                    #pragma unroll
                    for (int r = 0; r < 4; ++r) accB[nt][r] *= fq;
                mB = mnew;
            }
            float rs = 0.f;
            #pragma unroll
            for (int nt = 0; nt < 4; ++nt) {
                s16x4 pk;
                #pragma unroll
                for (int r = 0; r < 4; ++r) {
                    const float p = exp2f(scB[nt][r] - mB);
                    rs += p;
                    pk[r] = f2bs(p);
                }
                *(s16x4*)&Ps[wave][1][ln][16 * nt + 4 * lg] = pk;
            }
            rs += __shfl_xor(rs, 16, 64);
            rs += __shfl_xor(rs, 32, 64);
            lB += rs;
        }

        // ---- PV for both sets from SHARED V fragments ----
        const short8 paA0 = *(const short8*)&Ps[wave][0][ln][8 * lg];
        const short8 paA1 = *(const short8*)&Ps[wave][0][ln][32 + 8 * lg];
        const short8 paB0 = *(const short8*)&Ps[wave][1][ln][8 * lg];
        const short8 paB1 = *(const short8*)&Ps[wave][1][ln][32 + 8 * lg];
        #pragma unroll
        for (int nt = 0; nt < 4; ++nt) {
            short8 va0 = *(const short8*)&Vs[cur][sidx(16 * nt + ln, lg * 16)];
            short8 va1 = *(const short8*)&Vs[cur][sidx(16 * nt + ln, 64 + lg * 16)];
            accB[nt] = __builtin_amdgcn_mfma_f32_16x16x32_bf16(va0, paB0, accB[nt], 0, 0, 0);
            accB[nt] = __builtin_amdgcn_mfma_f32_16x16x32_bf16(va1, paB1, accB[nt], 0, 0, 0);
            if (doA) {
                accA[nt] = __builtin_amdgcn_mfma_f32_16x16x32_bf16(va0, paA0, accA[nt], 0, 0, 0);
                accA[nt] = __builtin_amdgcn_mfma_f32_16x16x32_bf16(va1, paA1, accA[nt], 0, 0, 0);
            }
        }

        if (t < qbB) {
            __syncthreads();
            cur ^= 1;
        }
    }

    // ---- epilogue: own-lane normalize (or vmean/1024), packed stores ----
    const float* vmb = vmean + (size_t)b * CC + h * HD;
    {
        const float rl = 1.f / lA;
        const bool dead = (mA == -FLT_MAX);
        const int s = qbA * 64 + wave * 16 + ln;
        short* crow = ctxT + ((size_t)b * SB + s) * CC + h * HD;
        #pragma unroll
        for (int nt = 0; nt < 4; ++nt) {
            const int d0 = 16 * nt + 4 * lg;
            const float4 vm4 = *(const float4*)&vmb[d0];
            s16x4 pk;
            pk[0] = f2bs(dead ? vm4.x * (1.f / 1024.f) : accA[nt][0] * rl);
            pk[1] = f2bs(dead ? vm4.y * (1.f / 1024.f) : accA[nt][1] * rl);
            pk[2] = f2bs(dead ? vm4.z * (1.f / 1024.f) : accA[nt][2] * rl);
            pk[3] = f2bs(dead ? vm4.w * (1.f / 1024.f) : accA[nt][3] * rl);
            *(s16x4*)&crow[d0] = pk;
        }
    }
    {
        const float rl = 1.f / lB;
        const bool dead = (mB == -FLT_MAX);
        const int s = qbB * 64 + wave * 16 + ln;
        short* crow = ctxT + ((size_t)b * SB + s) * CC + h * HD;
        #pragma unroll
        for (int nt = 0; nt < 4; ++nt) {
            const int d0 = 16 * nt + 4 * lg;
            const float4 vm4 = *(const float4*)&vmb[d0];
            s16x4 pk;
            pk[0] = f2bs(dead ? vm4.x * (1.f / 1024.f) : accB[nt][0] * rl);
            pk[1] = f2bs(dead ? vm4.y * (1.f / 1024.f) : accB[nt][1] * rl);
            pk[2] = f2bs(dead ? vm4.z * (1.f / 1024.f) : accB[nt][2] * rl);
            pk[3] = f2bs(dead ? vm4.w * (1.f / 1024.f) : accB[nt][3] * rl);
            *(s16x4*)&crow[d0] = pk;
        }
    }
}

extern "C" void kernel_launch(void* const* d_in, const int* in_sizes, int n_in,
                              void* d_out, int out_size, void* d_ws, size_t ws_size,
                              hipStream_t stream) {
    const float* x      = (const float*)d_in[0];
    const int*   amask  = (const int*)d_in[1];
    const float* qkv_w  = (const float*)d_in[2];
    const float* qkv_b  = (const float*)d_in[3];
    const float* proj_w = (const float*)d_in[4];
    const float* proj_b = (const float*)d_in[5];
    float* out = (float*)d_out;

    short* xT    = (short*)d_ws;                       // (B,S,C)
    short* w1b   = xT  + (size_t)NB * SB * CC;         // (1536,512)
    short* w2b   = w1b + (size_t)1536 * 512;           // (512,512)
    short* qT    = w2b + (size_t)512 * 512;            // (B,H,S,D)
    short* kT    = qT  + (size_t)NB * NH * SB * HD;    // (B,H,S,D)
    short* vN    = kT  + (size_t)NB * NH * SB * HD;    // (B,C,S)
    short* ctxT  = vN  + (size_t)NB * CC * SB;         // (B,S,C)
    float* vmean = (float*)(ctxT + (size_t)NB * SB * CC);  // (B,C) raw sums
    float* maskf = vmean + (size_t)NB * CC;            // (B,S)

    prep<<<2096, 256, 0, stream>>>(qkv_w, proj_w, w1b, w2b, x, xT,
                                   amask, maskf, vmean);
    gemm_bf16<0><<<dim3(8, 12, NB), 256, 0, stream>>>(
        w1b, qkv_b, xT, qT, kT, vN, nullptr, vmean);
    attn_mfma<<<dim3(512, 1, 1), 256, 0, stream>>>(qT, kT, vN, maskf, vmean, ctxT);
    gemm_bf16<1><<<dim3(8, 4, NB), 256, 0, stream>>>(
        w2b, proj_b, ctxT, nullptr, nullptr, nullptr, out, nullptr);
}